// Round 6
// baseline (463.683 us; speedup 1.0000x reference)
//
#include <hip/hip_runtime.h>
#include <math.h>

#define EMB 32
#define HID 16
#define BY 4
#define NSYMP 15
#define NOPT 3
#define XCOLS (BY + 1 + NSYMP)   // 20

#define BSHIFT 9                 // 512 nodes per tgt bucket
#define BSZ 512
#define EPB 8192                 // edges per hist/scatter block
#define NCH 4                    // src chunks (65536 nodes = 4 MiB of feature rows)
#define CSHIFT 16
#define NBINS_CAP 1600           // >= nbuck*NCH = 391*4 = 1564

#define SCAN_T 256
#define SCAN_E 32
#define SCAN_B (SCAN_T * SCAN_E)  // 8192 elements per scan block

// ---- level-1: per-block composite-bin histogram (LDS atomics only) ----
__global__ __launch_bounds__(256) void k_hist(const int* __restrict__ tgt,
                                              const int* __restrict__ src,
                                              unsigned int* __restrict__ H,
                                              int nE, int gb1, int nbins) {
    __shared__ unsigned int h[NBINS_CAP];
    int b = blockIdx.x, tid = threadIdx.x;
    for (int k = tid; k < nbins; k += 256) h[k] = 0;
    __syncthreads();
    int e0 = b * EPB;
    int ecnt = min(EPB, nE - e0);
    for (int k = tid; k < ecnt; k += 256) {
        int t = tgt[e0 + k], s = src[e0 + k];
        atomicAdd(&h[((unsigned)t >> BSHIFT) * NCH + ((unsigned)s >> CSHIFT)], 1u);
    }
    __syncthreads();
    for (int q = tid; q < nbins; q += 256) H[(size_t)q * gb1 + b] = h[q];
}

// ---- scan step 1: per-block sums ----
__global__ __launch_bounds__(256) void k_bsum(const unsigned int* __restrict__ A,
                                              unsigned int* __restrict__ bsum, int m) {
    __shared__ unsigned int s[SCAN_T];
    int base = blockIdx.x * SCAN_B + threadIdx.x * SCAN_E;
    unsigned int t = 0;
#pragma unroll
    for (int k = 0; k < SCAN_E; ++k) { int idx = base + k; if (idx < m) t += A[idx]; }
    s[threadIdx.x] = t; __syncthreads();
    for (int off = SCAN_T / 2; off > 0; off >>= 1) {
        if (threadIdx.x < off) s[threadIdx.x] += s[threadIdx.x + off];
        __syncthreads();
    }
    if (threadIdx.x == 0) bsum[blockIdx.x] = s[0];
}

// ---- scan step 2: exclusive scan of block sums (single block, nb <= 512) ----
__global__ __launch_bounds__(512) void k_bscan(const unsigned int* __restrict__ bsum,
                                               unsigned int* __restrict__ boff, int nb) {
    __shared__ unsigned int s[512];
    unsigned int v = (threadIdx.x < (unsigned)nb) ? bsum[threadIdx.x] : 0u;
    s[threadIdx.x] = v; __syncthreads();
    for (int off = 1; off < 512; off <<= 1) {
        unsigned int t = (threadIdx.x >= (unsigned)off) ? s[threadIdx.x - off] : 0u;
        __syncthreads();
        s[threadIdx.x] += t;
        __syncthreads();
    }
    if (threadIdx.x < (unsigned)nb) boff[threadIdx.x] = s[threadIdx.x] - v;
}

// ---- scan step 3: per-element exclusive prefix (+ sentinel S[m]=total) ----
__global__ __launch_bounds__(256) void k_scan2(const unsigned int* __restrict__ A,
                                               const unsigned int* __restrict__ boff,
                                               unsigned int* __restrict__ S, int m, int total) {
    __shared__ unsigned int s[SCAN_T];
    int tid = threadIdx.x;
    int base = blockIdx.x * SCAN_B + tid * SCAN_E;
    unsigned int t = 0;
#pragma unroll
    for (int k = 0; k < SCAN_E; ++k) { int idx = base + k; if (idx < m) t += A[idx]; }
    s[tid] = t; __syncthreads();
    unsigned int own = t;
    for (int off = 1; off < SCAN_T; off <<= 1) {
        unsigned int u = (tid >= off) ? s[tid - off] : 0u;
        __syncthreads();
        s[tid] += u;
        __syncthreads();
    }
    unsigned int run = boff[blockIdx.x] + s[tid] - own;
#pragma unroll
    for (int k = 0; k < SCAN_E; ++k) {
        int idx = base + k;
        if (idx < m) { S[idx] = run; run += A[idx]; }
    }
    if (blockIdx.x == 0 && tid == 0) S[m] = (unsigned int)total;
}

// ---- level-1 scatter, LDS-staged: edges -> (tbucket,chunk)-grouped packed array ----
__global__ __launch_bounds__(256) void k_scat(const int* __restrict__ tgt,
                                              const int* __restrict__ src,
                                              const unsigned int* __restrict__ S,
                                              int* __restrict__ bp,
                                              int nE, int gb1, int nbins) {
    __shared__ int bpv[EPB];                 // 32 KB staged payload
    __shared__ unsigned short qid[EPB];      // 16 KB bin id per slot
    __shared__ unsigned int cur[NBINS_CAP];  // 6.4 KB
    __shared__ unsigned int dif[NBINS_CAP];  // 6.4 KB
    __shared__ unsigned int ps[256];
    int b = blockIdx.x, tid = threadIdx.x;
    for (int k = tid; k < NBINS_CAP; k += 256) cur[k] = 0;
    __syncthreads();
    int e0 = b * EPB;
    int ecnt = min(EPB, nE - e0);

    // pass 1: local histogram
    for (int k = tid; k < ecnt; k += 256) {
        int t = tgt[e0 + k], s = src[e0 + k];
        atomicAdd(&cur[((unsigned)t >> BSHIFT) * NCH + ((unsigned)s >> CSHIFT)], 1u);
    }
    __syncthreads();

    // exclusive scan over NBINS_CAP bins, 8 per thread (cap >= nbins)
    unsigned int lv[8]; unsigned int tsum = 0;
#pragma unroll
    for (int k = 0; k < 8; ++k) {
        int f = 8 * tid + k;
        unsigned int d = (f < NBINS_CAP) ? cur[f] : 0u;
        lv[k] = tsum; tsum += d;
    }
    ps[tid] = tsum; __syncthreads();
    for (int off = 1; off < 256; off <<= 1) {
        unsigned int u = (tid >= off) ? ps[tid - off] : 0u;
        __syncthreads();
        ps[tid] += u;
        __syncthreads();
    }
    unsigned int excl = ps[tid] - tsum;
    __syncthreads();   // everyone done reading cur as histogram
#pragma unroll
    for (int k = 0; k < 8; ++k) {
        int f = 8 * tid + k;
        if (f < NBINS_CAP) { cur[f] = excl + lv[k]; dif[f] = excl + lv[k]; }
    }
    __syncthreads();
    for (int q = tid; q < nbins; q += 256)
        dif[q] = S[(size_t)q * gb1 + b] - dif[q];
    __syncthreads();

    // pass 2: scatter edges into LDS, grouped by bin
    for (int k = tid; k < ecnt; k += 256) {
        int t = tgt[e0 + k], s = src[e0 + k];
        int q = ((unsigned)t >> BSHIFT) * NCH + ((unsigned)s >> CSHIFT);
        unsigned int lpos = atomicAdd(&cur[q], 1u);
        bpv[lpos] = (s << BSHIFT) | (t & (BSZ - 1));
        qid[lpos] = (unsigned short)q;
    }
    __syncthreads();

    // pass 3: linear flush -> contiguous global writes per bin
    for (int k = tid; k < ecnt; k += 256) {
        int q = qid[k];
        bp[dif[q] + k] = bpv[k];
    }
}

// ---- level-2: per-tbucket fine CSR (node x chunk) + dinv ----
__global__ __launch_bounds__(256) void k_bcsr(const unsigned int* __restrict__ S,
                                              const int* __restrict__ bp,
                                              unsigned int* __restrict__ rowptr2,
                                              int* __restrict__ col,
                                              float* __restrict__ dinv,
                                              int n, int nE, int gb1, int nbuck) {
    __shared__ unsigned int h[BSZ * NCH];    // 2048 fine bins
    __shared__ unsigned int cur[BSZ * NCH];
    __shared__ unsigned int ps[256];
    int q = blockIdx.x, tid = threadIdx.x;
    int base = q << BSHIFT;
    for (int k = tid; k < BSZ * NCH; k += 256) h[k] = 0;
    __syncthreads();
    unsigned int e0 = S[(size_t)q * NCH * gb1];
    unsigned int e1 = S[(size_t)(q + 1) * NCH * gb1];
    for (unsigned int e = e0 + tid; e < e1; e += 256) {
        int v = bp[e];
        int f = (v & (BSZ - 1)) * NCH + ((unsigned)v >> (BSHIFT + CSHIFT));
        atomicAdd(&h[f], 1u);
    }
    __syncthreads();
    // scan 2048 bins, 8 per thread (thread t owns nodes 2t, 2t+1)
    unsigned int lv[8]; unsigned int tsum = 0;
#pragma unroll
    for (int k = 0; k < 8; ++k) { lv[k] = tsum; tsum += h[8 * tid + k]; }
    ps[tid] = tsum; __syncthreads();
    for (int off = 1; off < 256; off <<= 1) {
        unsigned int u = (tid >= off) ? ps[tid - off] : 0u;
        __syncthreads();
        ps[tid] += u;
        __syncthreads();
    }
    unsigned int excl = ps[tid] - tsum;
#pragma unroll
    for (int k = 0; k < 8; ++k) cur[8 * tid + k] = e0 + excl + lv[k];
    // rowptr2 entries: fine bin f=8t+k maps to rowptr2[base*NCH + f]
#pragma unroll
    for (int k = 0; k < 8; ++k) {
        int idx = base * NCH + 8 * tid + k;
        if (idx < n * NCH) rowptr2[idx] = e0 + excl + lv[k];
    }
    if (q == nbuck - 1 && tid == 0) rowptr2[n * NCH] = (unsigned int)nE;
    // dinv for nodes 2t, 2t+1
    int n0 = base + 2 * tid, n1 = n0 + 1;
    unsigned int d0 = h[8 * tid + 0] + h[8 * tid + 1] + h[8 * tid + 2] + h[8 * tid + 3];
    unsigned int d1 = h[8 * tid + 4] + h[8 * tid + 5] + h[8 * tid + 6] + h[8 * tid + 7];
    if (n0 < n) {
        float d = (float)(d0 + 1u); float r = rsqrtf(d);
        r = r * (1.5f - 0.5f * d * r * r); dinv[n0] = r;
    }
    if (n1 < n) {
        float d = (float)(d1 + 1u); float r = rsqrtf(d);
        r = r * (1.5f - 0.5f * d * r * r); dinv[n1] = r;
    }
    __syncthreads();
    for (unsigned int e = e0 + tid; e < e1; e += 256) {
        int v = bp[e];
        int f = (v & (BSZ - 1)) * NCH + ((unsigned)v >> (BSHIFT + CSHIFT));
        unsigned int slot = atomicAdd(&cur[f], 1u);
        col[slot] = (unsigned)v >> BSHIFT;
    }
}

// ---- embeddings + h@W1, pre-scaled by dinv ----
__global__ __launch_bounds__(256) void k_embed(const int* __restrict__ x,
                                               const float* __restrict__ birth_t,
                                               const float* __restrict__ gender_t,
                                               const float* __restrict__ symp_t,
                                               const float* __restrict__ W1,
                                               const float* __restrict__ dinv,
                                               float* __restrict__ hs1, int n) {
    __shared__ float sB[BY * EMB];
    __shared__ float sG[2 * EMB];
    __shared__ float sS[NSYMP * NOPT * EMB];
    __shared__ float sW[EMB * HID];
    for (int k = threadIdx.x; k < BY * EMB; k += blockDim.x) sB[k] = birth_t[k];
    for (int k = threadIdx.x; k < 2 * EMB; k += blockDim.x) sG[k] = gender_t[k];
    for (int k = threadIdx.x; k < NSYMP * NOPT * EMB; k += blockDim.x) sS[k] = symp_t[k];
    for (int k = threadIdx.x; k < EMB * HID; k += blockDim.x) sW[k] = W1[k];
    __syncthreads();

    int i = blockIdx.x * blockDim.x + threadIdx.x;
    if (i >= n) return;

    const int* xr = x + (size_t)i * XCOLS;
    int xv[XCOLS];
#pragma unroll
    for (int k = 0; k < XCOLS; ++k) xv[k] = xr[k];

    int bi = 0;
#pragma unroll
    for (int k = 1; k < BY; ++k) if (xv[k] > xv[bi]) bi = k;
    int gi = xv[BY];

    float ssum[EMB];
#pragma unroll
    for (int k = 0; k < EMB; ++k) ssum[k] = 0.f;
#pragma unroll
    for (int j = 0; j < NSYMP; ++j) {
        const float* row = &sS[(j * NOPT + xv[BY + 1 + j]) * EMB];
#pragma unroll
        for (int k = 0; k < EMB; ++k) ssum[k] += row[k];
    }

    float h[EMB];
#pragma unroll
    for (int k = 0; k < EMB; ++k)
        h[k] = (sB[bi * EMB + k] + sG[gi * EMB + k] + ssum[k] * (1.f / 15.f)) * (1.f / 3.f);

    float hp[HID];
#pragma unroll
    for (int j = 0; j < HID; ++j) hp[j] = 0.f;
#pragma unroll
    for (int k = 0; k < EMB; ++k) {
        float hv = h[k];
#pragma unroll
        for (int j = 0; j < HID; ++j) hp[j] += hv * sW[k * HID + j];
    }

    float dv = dinv[i];
    float4* o = (float4*)(hs1 + (size_t)i * HID);
#pragma unroll
    for (int q = 0; q < 4; ++q) {
        float4 v;
        v.x = dv * hp[q * 4 + 0];
        v.y = dv * hp[q * 4 + 1];
        v.z = dv * hp[q * 4 + 2];
        v.w = dv * hp[q * 4 + 3];
        o[q] = v;
    }
}

// ---- chunked CSR-pull partial aggregation: acc (+)= sum over chunk-c edges ----
__global__ __launch_bounds__(256) void k_gagg(const unsigned int* __restrict__ rowptr2,
                                              const int* __restrict__ col,
                                              const float* __restrict__ T,
                                              float* __restrict__ acc,
                                              int c, int first, int n) {
    int g = threadIdx.x >> 4, l = threadIdx.x & 15;
    int i = blockIdx.x * 16 + g;
    if (i >= n) return;
    unsigned int r0 = rowptr2[(size_t)i * NCH + c];
    unsigned int r1 = rowptr2[(size_t)i * NCH + c + 1];
    float s = 0.f;
    unsigned int e = r0;
    for (; e + 4 <= r1; e += 4) {
        int s0 = col[e], s1 = col[e + 1], s2 = col[e + 2], s3 = col[e + 3];
        float a0 = T[(size_t)s0 * HID + l];
        float a1 = T[(size_t)s1 * HID + l];
        float a2 = T[(size_t)s2 * HID + l];
        float a3 = T[(size_t)s3 * HID + l];
        s += (a0 + a1) + (a2 + a3);
    }
    for (; e < r1; ++e) s += T[(size_t)col[e] * HID + l];
    float* p = acc + (size_t)i * HID + l;
    if (first) *p = s; else *p += s;
}

// ---- last chunk + epilogue: ELU + W2 projection (layer 1 -> B) ----
__global__ __launch_bounds__(256) void k_gmid2(const unsigned int* __restrict__ rowptr2,
                                               const int* __restrict__ col,
                                               const float* __restrict__ A,
                                               const float* __restrict__ acc,
                                               const float* __restrict__ dinv,
                                               const float* __restrict__ W2,
                                               const float* __restrict__ b1,
                                               float* __restrict__ B, int n) {
    __shared__ float sW[HID * HID];
    __shared__ float sb[HID];
    if (threadIdx.x < HID * HID) sW[threadIdx.x] = W2[threadIdx.x];
    if (threadIdx.x < HID) sb[threadIdx.x] = b1[threadIdx.x];
    __syncthreads();

    int g = threadIdx.x >> 4, l = threadIdx.x & 15;
    int i = blockIdx.x * 16 + g;
    if (i >= n) return;

    unsigned int r0 = rowptr2[(size_t)i * NCH + (NCH - 1)];
    unsigned int r1 = rowptr2[(size_t)i * NCH + NCH];
    float s = 0.f;
    for (unsigned int e = r0; e < r1; ++e) s += A[(size_t)col[e] * HID + l];

    float dv = dinv[i];
    float v = dv * (acc[(size_t)i * HID + l] + s + A[(size_t)i * HID + l]) + sb[l];
    float h1 = (v > 0.f) ? v : expm1f(v);

    int base = (threadIdx.x & 63) & ~15;
    float hp = 0.f;
#pragma unroll
    for (int k = 0; k < HID; ++k) {
        float h1k = __shfl(h1, base + k, 64);
        hp += h1k * sW[k * HID + l];
    }
    B[(size_t)i * HID + l] = dv * hp;
}

// ---- last chunk + epilogue: final linear (layer 2 -> out) ----
__global__ __launch_bounds__(256) void k_gfin2(const unsigned int* __restrict__ rowptr2,
                                               const int* __restrict__ col,
                                               const float* __restrict__ B,
                                               const float* __restrict__ acc,
                                               const float* __restrict__ dinv,
                                               const float* __restrict__ b2,
                                               const float* __restrict__ Wl,
                                               const float* __restrict__ bl,
                                               float* __restrict__ out, int n) {
    __shared__ float sb[HID];
    __shared__ float sw[HID];
    __shared__ float sbl;
    if (threadIdx.x < HID) { sb[threadIdx.x] = b2[threadIdx.x]; sw[threadIdx.x] = Wl[threadIdx.x]; }
    if (threadIdx.x == 0) sbl = bl[0];
    __syncthreads();

    int g = threadIdx.x >> 4, l = threadIdx.x & 15;
    int i = blockIdx.x * 16 + g;
    if (i >= n) return;

    unsigned int r0 = rowptr2[(size_t)i * NCH + (NCH - 1)];
    unsigned int r1 = rowptr2[(size_t)i * NCH + NCH];
    float s = 0.f;
    for (unsigned int e = r0; e < r1; ++e) s += B[(size_t)col[e] * HID + l];

    float dv = dinv[i];
    float v = dv * (acc[(size_t)i * HID + l] + s + B[(size_t)i * HID + l]) + sb[l];
    float p = v * sw[l];
#pragma unroll
    for (int off = 8; off > 0; off >>= 1) p += __shfl_xor(p, off, 64);
    if (l == 0) out[i] = p + sbl;
}

extern "C" void kernel_launch(void* const* d_in, const int* in_sizes, int n_in,
                              void* d_out, int out_size, void* d_ws, size_t ws_size,
                              hipStream_t stream) {
    const int*   x        = (const int*)d_in[0];
    const int*   ei       = (const int*)d_in[1];   // int32 per harness conversion
    const float* birth_t  = (const float*)d_in[2];
    const float* gender_t = (const float*)d_in[3];
    const float* symp_t   = (const float*)d_in[4];
    const float* W1       = (const float*)d_in[5];
    const float* b1       = (const float*)d_in[6];
    const float* W2       = (const float*)d_in[7];
    const float* b2       = (const float*)d_in[8];
    const float* Wl       = (const float*)d_in[9];
    const float* bl       = (const float*)d_in[10];
    float*       out      = (float*)d_out;

    const int n  = in_sizes[0] / XCOLS;
    const int nE = in_sizes[1] / 2;
    const int* src = ei;
    const int* tgt = ei + nE;

    const int nbuck = (n + BSZ - 1) >> BSHIFT;            // 391
    const int nbins = nbuck * NCH;                        // 1564 (<= NBINS_CAP)
    const int gb1   = (nE + EPB - 1) / EPB;               // 782
    const int M     = nbins * gb1;                        // ~1.22M
    const int nb    = (M + SCAN_B - 1) / SCAN_B;          // ~150 (<=512)

    // workspace layout (256B aligned slices)
    char* ws = (char*)d_ws;
    size_t off = 0;
    auto alloc = [&](size_t bytes) { char* p = ws + off; off = (off + bytes + 255) & ~(size_t)255; return p; };
    unsigned int* H       = (unsigned int*)alloc((size_t)M * 4);
    unsigned int* S       = (unsigned int*)alloc(((size_t)M + 1) * 4);
    unsigned int* bsum    = (unsigned int*)alloc(512 * 4);
    unsigned int* boff    = (unsigned int*)alloc(512 * 4);
    int*          bp      = (int*)alloc((size_t)nE * 4);
    int*          col     = (int*)alloc((size_t)nE * 4);
    unsigned int* rowptr2 = (unsigned int*)alloc(((size_t)n * NCH + 1) * 4);
    float*        dinv    = (float*)alloc((size_t)n * 4);
    float*        acc     = (float*)alloc((size_t)n * HID * 4);
    float*        A       = (float*)alloc((size_t)n * HID * 4);
    float*        B       = (float*)alloc((size_t)n * HID * 4);

    const int BLK = 256;
    const int gN    = (n + BLK - 1) / BLK;
    const int gNode = (n + 15) / 16;

    k_hist <<<gb1, BLK, 0, stream>>>(tgt, src, H, nE, gb1, nbins);
    k_bsum <<<nb, SCAN_T, 0, stream>>>(H, bsum, M);
    k_bscan<<<1, 512, 0, stream>>>(bsum, boff, nb);
    k_scan2<<<nb, SCAN_T, 0, stream>>>(H, boff, S, M, nE);
    k_scat <<<gb1, BLK, 0, stream>>>(tgt, src, S, bp, nE, gb1, nbins);
    k_bcsr <<<nbuck, BLK, 0, stream>>>(S, bp, rowptr2, col, dinv, n, nE, gb1, nbuck);
    k_embed<<<gN, BLK, 0, stream>>>(x, birth_t, gender_t, symp_t, W1, dinv, A, n);

    // layer 1: chunk-phased aggregation over A, fused epilogue on last chunk
    k_gagg <<<gNode, BLK, 0, stream>>>(rowptr2, col, A, acc, 0, 1, n);
    k_gagg <<<gNode, BLK, 0, stream>>>(rowptr2, col, A, acc, 1, 0, n);
    k_gagg <<<gNode, BLK, 0, stream>>>(rowptr2, col, A, acc, 2, 0, n);
    k_gmid2<<<gNode, BLK, 0, stream>>>(rowptr2, col, A, acc, dinv, W2, b1, B, n);

    // layer 2: same over B, fused final linear
    k_gagg <<<gNode, BLK, 0, stream>>>(rowptr2, col, B, acc, 0, 1, n);
    k_gagg <<<gNode, BLK, 0, stream>>>(rowptr2, col, B, acc, 1, 0, n);
    k_gagg <<<gNode, BLK, 0, stream>>>(rowptr2, col, B, acc, 2, 0, n);
    k_gfin2<<<gNode, BLK, 0, stream>>>(rowptr2, col, B, acc, dinv, b2, Wl, bl, out, n);
}

// Round 7
// 352.184 us; speedup vs baseline: 1.3166x; 1.3166x over previous
//
#include <hip/hip_runtime.h>
#include <math.h>

#define EMB 32
#define HID 16
#define BY 4
#define NSYMP 15
#define NOPT 3
#define XCOLS (BY + 1 + NSYMP)   // 20

#define BSHIFT 9                 // 512 nodes per tgt bucket
#define BSZ 512
#define EPB 8192                 // edges per hist/scatter block
#define NCH 4                    // src chunks (65536 nodes = 4 MiB of feature rows)
#define CSHIFT 16
#define NBINS_CAP 1600           // >= nbuck*NCH = 391*4 = 1564

#define SCAN_T 256
#define SCAN_E 32
#define SCAN_B (SCAN_T * SCAN_E)  // 8192 elements per scan block

// ---- level-1: per-block composite-bin histogram (LDS atomics only) ----
__global__ __launch_bounds__(256) void k_hist(const int* __restrict__ tgt,
                                              const int* __restrict__ src,
                                              unsigned int* __restrict__ H,
                                              int nE, int gb1, int nbins) {
    __shared__ unsigned int h[NBINS_CAP];
    int b = blockIdx.x, tid = threadIdx.x;
    for (int k = tid; k < nbins; k += 256) h[k] = 0;
    __syncthreads();
    int e0 = b * EPB;
    int ecnt = min(EPB, nE - e0);
    for (int k = tid; k < ecnt; k += 256) {
        int t = tgt[e0 + k], s = src[e0 + k];
        atomicAdd(&h[((unsigned)t >> BSHIFT) * NCH + ((unsigned)s >> CSHIFT)], 1u);
    }
    __syncthreads();
    for (int q = tid; q < nbins; q += 256) H[(size_t)q * gb1 + b] = h[q];
}

// ---- scan step 1: per-block sums ----
__global__ __launch_bounds__(256) void k_bsum(const unsigned int* __restrict__ A,
                                              unsigned int* __restrict__ bsum, int m) {
    __shared__ unsigned int s[SCAN_T];
    int base = blockIdx.x * SCAN_B + threadIdx.x * SCAN_E;
    unsigned int t = 0;
#pragma unroll
    for (int k = 0; k < SCAN_E; ++k) { int idx = base + k; if (idx < m) t += A[idx]; }
    s[threadIdx.x] = t; __syncthreads();
    for (int off = SCAN_T / 2; off > 0; off >>= 1) {
        if (threadIdx.x < off) s[threadIdx.x] += s[threadIdx.x + off];
        __syncthreads();
    }
    if (threadIdx.x == 0) bsum[blockIdx.x] = s[0];
}

// ---- scan step 2: exclusive scan of block sums (single block, nb <= 512) ----
__global__ __launch_bounds__(512) void k_bscan(const unsigned int* __restrict__ bsum,
                                               unsigned int* __restrict__ boff, int nb) {
    __shared__ unsigned int s[512];
    unsigned int v = (threadIdx.x < (unsigned)nb) ? bsum[threadIdx.x] : 0u;
    s[threadIdx.x] = v; __syncthreads();
    for (int off = 1; off < 512; off <<= 1) {
        unsigned int t = (threadIdx.x >= (unsigned)off) ? s[threadIdx.x - off] : 0u;
        __syncthreads();
        s[threadIdx.x] += t;
        __syncthreads();
    }
    if (threadIdx.x < (unsigned)nb) boff[threadIdx.x] = s[threadIdx.x] - v;
}

// ---- scan step 3: per-element exclusive prefix (+ sentinel S[m]=total) ----
__global__ __launch_bounds__(256) void k_scan2(const unsigned int* __restrict__ A,
                                               const unsigned int* __restrict__ boff,
                                               unsigned int* __restrict__ S, int m, int total) {
    __shared__ unsigned int s[SCAN_T];
    int tid = threadIdx.x;
    int base = blockIdx.x * SCAN_B + tid * SCAN_E;
    unsigned int t = 0;
#pragma unroll
    for (int k = 0; k < SCAN_E; ++k) { int idx = base + k; if (idx < m) t += A[idx]; }
    s[tid] = t; __syncthreads();
    unsigned int own = t;
    for (int off = 1; off < SCAN_T; off <<= 1) {
        unsigned int u = (tid >= off) ? s[tid - off] : 0u;
        __syncthreads();
        s[tid] += u;
        __syncthreads();
    }
    unsigned int run = boff[blockIdx.x] + s[tid] - own;
#pragma unroll
    for (int k = 0; k < SCAN_E; ++k) {
        int idx = base + k;
        if (idx < m) { S[idx] = run; run += A[idx]; }
    }
    if (blockIdx.x == 0 && tid == 0) S[m] = (unsigned int)total;
}

// ---- level-1 scatter, LDS-staged: edges -> (tbucket,chunk)-grouped packed array ----
__global__ __launch_bounds__(256) void k_scat(const int* __restrict__ tgt,
                                              const int* __restrict__ src,
                                              const unsigned int* __restrict__ S,
                                              int* __restrict__ bp,
                                              int nE, int gb1, int nbins) {
    __shared__ int bpv[EPB];                 // 32 KB staged payload
    __shared__ unsigned short qid[EPB];      // 16 KB bin id per slot
    __shared__ unsigned int cur[NBINS_CAP];  // 6.4 KB
    __shared__ unsigned int dif[NBINS_CAP];  // 6.4 KB
    __shared__ unsigned int ps[256];
    int b = blockIdx.x, tid = threadIdx.x;
    for (int k = tid; k < NBINS_CAP; k += 256) cur[k] = 0;
    __syncthreads();
    int e0 = b * EPB;
    int ecnt = min(EPB, nE - e0);

    // pass 1: local histogram
    for (int k = tid; k < ecnt; k += 256) {
        int t = tgt[e0 + k], s = src[e0 + k];
        atomicAdd(&cur[((unsigned)t >> BSHIFT) * NCH + ((unsigned)s >> CSHIFT)], 1u);
    }
    __syncthreads();

    // exclusive scan over NBINS_CAP bins, 8 per thread (cap >= nbins)
    unsigned int lv[8]; unsigned int tsum = 0;
#pragma unroll
    for (int k = 0; k < 8; ++k) {
        int f = 8 * tid + k;
        unsigned int d = (f < NBINS_CAP) ? cur[f] : 0u;
        lv[k] = tsum; tsum += d;
    }
    ps[tid] = tsum; __syncthreads();
    for (int off = 1; off < 256; off <<= 1) {
        unsigned int u = (tid >= off) ? ps[tid - off] : 0u;
        __syncthreads();
        ps[tid] += u;
        __syncthreads();
    }
    unsigned int excl = ps[tid] - tsum;
    __syncthreads();   // everyone done reading cur as histogram
#pragma unroll
    for (int k = 0; k < 8; ++k) {
        int f = 8 * tid + k;
        if (f < NBINS_CAP) { cur[f] = excl + lv[k]; dif[f] = excl + lv[k]; }
    }
    __syncthreads();
    for (int q = tid; q < nbins; q += 256)
        dif[q] = S[(size_t)q * gb1 + b] - dif[q];
    __syncthreads();

    // pass 2: scatter edges into LDS, grouped by bin
    for (int k = tid; k < ecnt; k += 256) {
        int t = tgt[e0 + k], s = src[e0 + k];
        int q = ((unsigned)t >> BSHIFT) * NCH + ((unsigned)s >> CSHIFT);
        unsigned int lpos = atomicAdd(&cur[q], 1u);
        bpv[lpos] = (s << BSHIFT) | (t & (BSZ - 1));
        qid[lpos] = (unsigned short)q;
    }
    __syncthreads();

    // pass 3: linear flush -> contiguous global writes per bin
    for (int k = tid; k < ecnt; k += 256) {
        int q = qid[k];
        bp[dif[q] + k] = bpv[k];
    }
}

// ---- level-2: per-tbucket fine CSR (node x chunk) + dinv ----
__global__ __launch_bounds__(256) void k_bcsr(const unsigned int* __restrict__ S,
                                              const int* __restrict__ bp,
                                              unsigned int* __restrict__ rowptr2,
                                              int* __restrict__ col,
                                              float* __restrict__ dinv,
                                              int n, int nE, int gb1, int nbuck) {
    __shared__ unsigned int h[BSZ * NCH];    // 2048 fine bins
    __shared__ unsigned int cur[BSZ * NCH];
    __shared__ unsigned int ps[256];
    int q = blockIdx.x, tid = threadIdx.x;
    int base = q << BSHIFT;
    for (int k = tid; k < BSZ * NCH; k += 256) h[k] = 0;
    __syncthreads();
    unsigned int e0 = S[(size_t)q * NCH * gb1];
    unsigned int e1 = S[(size_t)(q + 1) * NCH * gb1];
    for (unsigned int e = e0 + tid; e < e1; e += 256) {
        int v = bp[e];
        int f = (v & (BSZ - 1)) * NCH + ((unsigned)v >> (BSHIFT + CSHIFT));
        atomicAdd(&h[f], 1u);
    }
    __syncthreads();
    // scan 2048 bins, 8 per thread (thread t owns nodes 2t, 2t+1)
    unsigned int lv[8]; unsigned int tsum = 0;
#pragma unroll
    for (int k = 0; k < 8; ++k) { lv[k] = tsum; tsum += h[8 * tid + k]; }
    ps[tid] = tsum; __syncthreads();
    for (int off = 1; off < 256; off <<= 1) {
        unsigned int u = (tid >= off) ? ps[tid - off] : 0u;
        __syncthreads();
        ps[tid] += u;
        __syncthreads();
    }
    unsigned int excl = ps[tid] - tsum;
#pragma unroll
    for (int k = 0; k < 8; ++k) cur[8 * tid + k] = e0 + excl + lv[k];
#pragma unroll
    for (int k = 0; k < 8; ++k) {
        int idx = base * NCH + 8 * tid + k;
        if (idx < n * NCH) rowptr2[idx] = e0 + excl + lv[k];
    }
    if (q == nbuck - 1 && tid == 0) rowptr2[n * NCH] = (unsigned int)nE;
    int n0 = base + 2 * tid, n1 = n0 + 1;
    unsigned int d0 = h[8 * tid + 0] + h[8 * tid + 1] + h[8 * tid + 2] + h[8 * tid + 3];
    unsigned int d1 = h[8 * tid + 4] + h[8 * tid + 5] + h[8 * tid + 6] + h[8 * tid + 7];
    if (n0 < n) {
        float d = (float)(d0 + 1u); float r = rsqrtf(d);
        r = r * (1.5f - 0.5f * d * r * r); dinv[n0] = r;
    }
    if (n1 < n) {
        float d = (float)(d1 + 1u); float r = rsqrtf(d);
        r = r * (1.5f - 0.5f * d * r * r); dinv[n1] = r;
    }
    __syncthreads();
    for (unsigned int e = e0 + tid; e < e1; e += 256) {
        int v = bp[e];
        int f = (v & (BSZ - 1)) * NCH + ((unsigned)v >> (BSHIFT + CSHIFT));
        unsigned int slot = atomicAdd(&cur[f], 1u);
        col[slot] = (unsigned)v >> BSHIFT;
    }
}

// ---- embeddings + h@W1, pre-scaled by dinv ----
__global__ __launch_bounds__(256) void k_embed(const int* __restrict__ x,
                                               const float* __restrict__ birth_t,
                                               const float* __restrict__ gender_t,
                                               const float* __restrict__ symp_t,
                                               const float* __restrict__ W1,
                                               const float* __restrict__ dinv,
                                               float* __restrict__ hs1, int n) {
    __shared__ float sB[BY * EMB];
    __shared__ float sG[2 * EMB];
    __shared__ float sS[NSYMP * NOPT * EMB];
    __shared__ float sW[EMB * HID];
    for (int k = threadIdx.x; k < BY * EMB; k += blockDim.x) sB[k] = birth_t[k];
    for (int k = threadIdx.x; k < 2 * EMB; k += blockDim.x) sG[k] = gender_t[k];
    for (int k = threadIdx.x; k < NSYMP * NOPT * EMB; k += blockDim.x) sS[k] = symp_t[k];
    for (int k = threadIdx.x; k < EMB * HID; k += blockDim.x) sW[k] = W1[k];
    __syncthreads();

    int i = blockIdx.x * blockDim.x + threadIdx.x;
    if (i >= n) return;

    const int* xr = x + (size_t)i * XCOLS;
    int xv[XCOLS];
#pragma unroll
    for (int k = 0; k < XCOLS; ++k) xv[k] = xr[k];

    int bi = 0;
#pragma unroll
    for (int k = 1; k < BY; ++k) if (xv[k] > xv[bi]) bi = k;
    int gi = xv[BY];

    float ssum[EMB];
#pragma unroll
    for (int k = 0; k < EMB; ++k) ssum[k] = 0.f;
#pragma unroll
    for (int j = 0; j < NSYMP; ++j) {
        const float* row = &sS[(j * NOPT + xv[BY + 1 + j]) * EMB];
#pragma unroll
        for (int k = 0; k < EMB; ++k) ssum[k] += row[k];
    }

    float h[EMB];
#pragma unroll
    for (int k = 0; k < EMB; ++k)
        h[k] = (sB[bi * EMB + k] + sG[gi * EMB + k] + ssum[k] * (1.f / 15.f)) * (1.f / 3.f);

    float hp[HID];
#pragma unroll
    for (int j = 0; j < HID; ++j) hp[j] = 0.f;
#pragma unroll
    for (int k = 0; k < EMB; ++k) {
        float hv = h[k];
#pragma unroll
        for (int j = 0; j < HID; ++j) hp[j] += hv * sW[k * HID + j];
    }

    float dv = dinv[i];
    float4* o = (float4*)(hs1 + (size_t)i * HID);
#pragma unroll
    for (int q = 0; q < 4; ++q) {
        float4 v;
        v.x = dv * hp[q * 4 + 0];
        v.y = dv * hp[q * 4 + 1];
        v.z = dv * hp[q * 4 + 2];
        v.w = dv * hp[q * 4 + 3];
        o[q] = v;
    }
}

// ---- layer 1 full: CSR gather (chunk-ordered) + ELU + W2 + z = hs2 . Wl ----
// 16 lanes per node; per-node edge range is internally chunk-sorted, giving
// phase-coherent L2 access without extra passes.
__global__ __launch_bounds__(256) void k_gmid3(const unsigned int* __restrict__ rowptr2,
                                               const int* __restrict__ col,
                                               const float* __restrict__ A,
                                               const float* __restrict__ dinv,
                                               const float* __restrict__ W2,
                                               const float* __restrict__ b1,
                                               const float* __restrict__ Wl,
                                               float* __restrict__ z, int n) {
    __shared__ float sW[HID * HID];
    __shared__ float sb[HID];
    __shared__ float sw[HID];
    if (threadIdx.x < HID * HID) sW[threadIdx.x] = W2[threadIdx.x];
    if (threadIdx.x < HID) { sb[threadIdx.x] = b1[threadIdx.x]; sw[threadIdx.x] = Wl[threadIdx.x]; }
    __syncthreads();

    int g = threadIdx.x >> 4, l = threadIdx.x & 15;
    int i = blockIdx.x * 16 + g;
    if (i >= n) return;

    unsigned int r0 = rowptr2[(size_t)i * NCH];
    unsigned int r1 = rowptr2[(size_t)i * NCH + NCH];
    float acc = 0.f;
    unsigned int e = r0;
    for (; e + 4 <= r1; e += 4) {
        int s0 = col[e], s1 = col[e + 1], s2 = col[e + 2], s3 = col[e + 3];
        float a0 = A[(size_t)s0 * HID + l];
        float a1 = A[(size_t)s1 * HID + l];
        float a2 = A[(size_t)s2 * HID + l];
        float a3 = A[(size_t)s3 * HID + l];
        acc += (a0 + a1) + (a2 + a3);
    }
    for (; e < r1; ++e) acc += A[(size_t)col[e] * HID + l];

    float dv = dinv[i];
    float v = dv * (acc + A[(size_t)i * HID + l]) + sb[l];
    float h1 = (v > 0.f) ? v : expm1f(v);

    int base = (threadIdx.x & 63) & ~15;
    float hp = 0.f;
#pragma unroll
    for (int k = 0; k < HID; ++k) {
        float h1k = __shfl(h1, base + k, 64);
        hp += h1k * sW[k * HID + l];
    }
    // z[i] = (dv*hp) . Wl   (16-lane reduce)
    float p = dv * hp * sw[l];
#pragma unroll
    for (int off = 8; off > 0; off >>= 1) p += __shfl_xor(p, off, 64);
    if (l == 0) z[i] = p;
}

// ---- layer 2 full: scalar gather of z + final affine ----
__global__ __launch_bounds__(256) void k_gfin3(const unsigned int* __restrict__ rowptr2,
                                               const int* __restrict__ col,
                                               const float* __restrict__ z,
                                               const float* __restrict__ dinv,
                                               const float* __restrict__ b2,
                                               const float* __restrict__ Wl,
                                               const float* __restrict__ bl,
                                               float* __restrict__ out, int n) {
    __shared__ float sc0;
    if (threadIdx.x == 0) {
        float c = 0.f;
#pragma unroll
        for (int k = 0; k < HID; ++k) c += b2[k] * Wl[k];
        sc0 = c + bl[0];
    }
    __syncthreads();

    int i = blockIdx.x * blockDim.x + threadIdx.x;
    if (i >= n) return;

    unsigned int r0 = rowptr2[(size_t)i * NCH];
    unsigned int r1 = rowptr2[(size_t)i * NCH + NCH];
    float s = 0.f;
    unsigned int e = r0;
    for (; e + 4 <= r1; e += 4) {
        float a0 = z[col[e]], a1 = z[col[e + 1]], a2 = z[col[e + 2]], a3 = z[col[e + 3]];
        s += (a0 + a1) + (a2 + a3);
    }
    for (; e < r1; ++e) s += z[col[e]];
    out[i] = dinv[i] * (s + z[i]) + sc0;
}

extern "C" void kernel_launch(void* const* d_in, const int* in_sizes, int n_in,
                              void* d_out, int out_size, void* d_ws, size_t ws_size,
                              hipStream_t stream) {
    const int*   x        = (const int*)d_in[0];
    const int*   ei       = (const int*)d_in[1];   // int32 per harness conversion
    const float* birth_t  = (const float*)d_in[2];
    const float* gender_t = (const float*)d_in[3];
    const float* symp_t   = (const float*)d_in[4];
    const float* W1       = (const float*)d_in[5];
    const float* b1       = (const float*)d_in[6];
    const float* W2       = (const float*)d_in[7];
    const float* b2       = (const float*)d_in[8];
    const float* Wl       = (const float*)d_in[9];
    const float* bl       = (const float*)d_in[10];
    float*       out      = (float*)d_out;

    const int n  = in_sizes[0] / XCOLS;
    const int nE = in_sizes[1] / 2;
    const int* src = ei;
    const int* tgt = ei + nE;

    const int nbuck = (n + BSZ - 1) >> BSHIFT;            // 391
    const int nbins = nbuck * NCH;                        // 1564 (<= NBINS_CAP)
    const int gb1   = (nE + EPB - 1) / EPB;               // 782
    const int M     = nbins * gb1;                        // ~1.22M
    const int nb    = (M + SCAN_B - 1) / SCAN_B;          // ~150 (<=512)

    // workspace layout (256B aligned slices)
    char* ws = (char*)d_ws;
    size_t off = 0;
    auto alloc = [&](size_t bytes) { char* p = ws + off; off = (off + bytes + 255) & ~(size_t)255; return p; };
    unsigned int* H       = (unsigned int*)alloc((size_t)M * 4);
    unsigned int* S       = (unsigned int*)alloc(((size_t)M + 1) * 4);
    unsigned int* bsum    = (unsigned int*)alloc(512 * 4);
    unsigned int* boff    = (unsigned int*)alloc(512 * 4);
    int*          bp      = (int*)alloc((size_t)nE * 4);
    int*          col     = (int*)alloc((size_t)nE * 4);
    unsigned int* rowptr2 = (unsigned int*)alloc(((size_t)n * NCH + 1) * 4);
    float*        dinv    = (float*)alloc((size_t)n * 4);
    float*        A       = (float*)alloc((size_t)n * HID * 4);
    float*        z       = (float*)alloc((size_t)n * 4);

    const int BLK = 256;
    const int gN    = (n + BLK - 1) / BLK;
    const int gNode = (n + 15) / 16;

    k_hist <<<gb1, BLK, 0, stream>>>(tgt, src, H, nE, gb1, nbins);
    k_bsum <<<nb, SCAN_T, 0, stream>>>(H, bsum, M);
    k_bscan<<<1, 512, 0, stream>>>(bsum, boff, nb);
    k_scan2<<<nb, SCAN_T, 0, stream>>>(H, boff, S, M, nE);
    k_scat <<<gb1, BLK, 0, stream>>>(tgt, src, S, bp, nE, gb1, nbins);
    k_bcsr <<<nbuck, BLK, 0, stream>>>(S, bp, rowptr2, col, dinv, n, nE, gb1, nbuck);
    k_embed<<<gN, BLK, 0, stream>>>(x, birth_t, gender_t, symp_t, W1, dinv, A, n);
    k_gmid3<<<gNode, BLK, 0, stream>>>(rowptr2, col, A, dinv, W2, b1, Wl, z, n);
    k_gfin3<<<gN, BLK, 0, stream>>>(rowptr2, col, z, dinv, b2, Wl, bl, out, n);
}

// Round 8
// 340.947 us; speedup vs baseline: 1.3600x; 1.0330x over previous
//
#include <hip/hip_runtime.h>
#include <math.h>

#define EMB 32
#define HID 16
#define BY 4
#define NSYMP 15
#define NOPT 3
#define XCOLS (BY + 1 + NSYMP)   // 20

#define BSHIFT 9                 // 512 nodes per tgt bucket
#define BSZ 512
#define EPB 8192                 // edges per hist/scatter block
#define NCH 4                    // src chunks (65536 nodes = 4 MiB of feature rows)
#define CSHIFT 16
#define NBINS_CAP 1600           // >= nbuck*NCH = 391*4 = 1564

#define SCAN_T 256
#define SCAN_E 32
#define SCAN_B (SCAN_T * SCAN_E)  // 8192 elements per scan block

// ---- level-1: per-block composite-bin histogram (LDS atomics only) ----
__global__ __launch_bounds__(256) void k_hist(const int* __restrict__ tgt,
                                              const int* __restrict__ src,
                                              unsigned int* __restrict__ H,
                                              int nE, int gb1, int nbins) {
    __shared__ unsigned int h[NBINS_CAP];
    int b = blockIdx.x, tid = threadIdx.x;
    for (int k = tid; k < nbins; k += 256) h[k] = 0;
    __syncthreads();
    int e0 = b * EPB;
    int ecnt = min(EPB, nE - e0);
    for (int k = tid; k < ecnt; k += 256) {
        int t = tgt[e0 + k], s = src[e0 + k];
        atomicAdd(&h[((unsigned)t >> BSHIFT) * NCH + ((unsigned)s >> CSHIFT)], 1u);
    }
    __syncthreads();
    for (int q = tid; q < nbins; q += 256) H[(size_t)q * gb1 + b] = h[q];
}

// ---- scan step 1: per-block sums ----
__global__ __launch_bounds__(256) void k_bsum(const unsigned int* __restrict__ A,
                                              unsigned int* __restrict__ bsum, int m) {
    __shared__ unsigned int s[SCAN_T];
    int base = blockIdx.x * SCAN_B + threadIdx.x * SCAN_E;
    unsigned int t = 0;
#pragma unroll
    for (int k = 0; k < SCAN_E; ++k) { int idx = base + k; if (idx < m) t += A[idx]; }
    s[threadIdx.x] = t; __syncthreads();
    for (int off = SCAN_T / 2; off > 0; off >>= 1) {
        if (threadIdx.x < off) s[threadIdx.x] += s[threadIdx.x + off];
        __syncthreads();
    }
    if (threadIdx.x == 0) bsum[blockIdx.x] = s[0];
}

// ---- scan step 2: exclusive scan of block sums (single block, nb <= 512) ----
__global__ __launch_bounds__(512) void k_bscan(const unsigned int* __restrict__ bsum,
                                               unsigned int* __restrict__ boff, int nb) {
    __shared__ unsigned int s[512];
    unsigned int v = (threadIdx.x < (unsigned)nb) ? bsum[threadIdx.x] : 0u;
    s[threadIdx.x] = v; __syncthreads();
    for (int off = 1; off < 512; off <<= 1) {
        unsigned int t = (threadIdx.x >= (unsigned)off) ? s[threadIdx.x - off] : 0u;
        __syncthreads();
        s[threadIdx.x] += t;
        __syncthreads();
    }
    if (threadIdx.x < (unsigned)nb) boff[threadIdx.x] = s[threadIdx.x] - v;
}

// ---- scan step 3: per-element exclusive prefix (+ sentinel S[m]=total) ----
__global__ __launch_bounds__(256) void k_scan2(const unsigned int* __restrict__ A,
                                               const unsigned int* __restrict__ boff,
                                               unsigned int* __restrict__ S, int m, int total) {
    __shared__ unsigned int s[SCAN_T];
    int tid = threadIdx.x;
    int base = blockIdx.x * SCAN_B + tid * SCAN_E;
    unsigned int t = 0;
#pragma unroll
    for (int k = 0; k < SCAN_E; ++k) { int idx = base + k; if (idx < m) t += A[idx]; }
    s[tid] = t; __syncthreads();
    unsigned int own = t;
    for (int off = 1; off < SCAN_T; off <<= 1) {
        unsigned int u = (tid >= off) ? s[tid - off] : 0u;
        __syncthreads();
        s[tid] += u;
        __syncthreads();
    }
    unsigned int run = boff[blockIdx.x] + s[tid] - own;
#pragma unroll
    for (int k = 0; k < SCAN_E; ++k) {
        int idx = base + k;
        if (idx < m) { S[idx] = run; run += A[idx]; }
    }
    if (blockIdx.x == 0 && tid == 0) S[m] = (unsigned int)total;
}

// ---- level-1 scatter, LDS-staged: edges -> (tbucket,chunk)-grouped packed array ----
__global__ __launch_bounds__(256) void k_scat(const int* __restrict__ tgt,
                                              const int* __restrict__ src,
                                              const unsigned int* __restrict__ S,
                                              int* __restrict__ bp,
                                              int nE, int gb1, int nbins) {
    __shared__ int bpv[EPB];                 // 32 KB staged payload
    __shared__ unsigned short qid[EPB];      // 16 KB bin id per slot
    __shared__ unsigned int cur[NBINS_CAP];  // 6.4 KB
    __shared__ unsigned int dif[NBINS_CAP];  // 6.4 KB
    __shared__ unsigned int ps[256];
    int b = blockIdx.x, tid = threadIdx.x;
    for (int k = tid; k < NBINS_CAP; k += 256) cur[k] = 0;
    __syncthreads();
    int e0 = b * EPB;
    int ecnt = min(EPB, nE - e0);

    // pass 1: local histogram
    for (int k = tid; k < ecnt; k += 256) {
        int t = tgt[e0 + k], s = src[e0 + k];
        atomicAdd(&cur[((unsigned)t >> BSHIFT) * NCH + ((unsigned)s >> CSHIFT)], 1u);
    }
    __syncthreads();

    // exclusive scan over NBINS_CAP bins, 8 per thread (cap >= nbins)
    unsigned int lv[8]; unsigned int tsum = 0;
#pragma unroll
    for (int k = 0; k < 8; ++k) {
        int f = 8 * tid + k;
        unsigned int d = (f < NBINS_CAP) ? cur[f] : 0u;
        lv[k] = tsum; tsum += d;
    }
    ps[tid] = tsum; __syncthreads();
    for (int off = 1; off < 256; off <<= 1) {
        unsigned int u = (tid >= off) ? ps[tid - off] : 0u;
        __syncthreads();
        ps[tid] += u;
        __syncthreads();
    }
    unsigned int excl = ps[tid] - tsum;
    __syncthreads();   // everyone done reading cur as histogram
#pragma unroll
    for (int k = 0; k < 8; ++k) {
        int f = 8 * tid + k;
        if (f < NBINS_CAP) { cur[f] = excl + lv[k]; dif[f] = excl + lv[k]; }
    }
    __syncthreads();
    for (int q = tid; q < nbins; q += 256)
        dif[q] = S[(size_t)q * gb1 + b] - dif[q];
    __syncthreads();

    // pass 2: scatter edges into LDS, grouped by bin
    for (int k = tid; k < ecnt; k += 256) {
        int t = tgt[e0 + k], s = src[e0 + k];
        int q = ((unsigned)t >> BSHIFT) * NCH + ((unsigned)s >> CSHIFT);
        unsigned int lpos = atomicAdd(&cur[q], 1u);
        bpv[lpos] = (s << BSHIFT) | (t & (BSZ - 1));
        qid[lpos] = (unsigned short)q;
    }
    __syncthreads();

    // pass 3: linear flush -> contiguous global writes per bin
    for (int k = tid; k < ecnt; k += 256) {
        int q = qid[k];
        bp[dif[q] + k] = bpv[k];
    }
}

// ---- level-2: per-tbucket fine CSR (node x chunk) + dinv ----
__global__ __launch_bounds__(256) void k_bcsr(const unsigned int* __restrict__ S,
                                              const int* __restrict__ bp,
                                              unsigned int* __restrict__ rowptr2,
                                              int* __restrict__ col,
                                              float* __restrict__ dinv,
                                              int n, int nE, int gb1, int nbuck) {
    __shared__ unsigned int h[BSZ * NCH];    // 2048 fine bins
    __shared__ unsigned int cur[BSZ * NCH];
    __shared__ unsigned int ps[256];
    int q = blockIdx.x, tid = threadIdx.x;
    int base = q << BSHIFT;
    for (int k = tid; k < BSZ * NCH; k += 256) h[k] = 0;
    __syncthreads();
    unsigned int e0 = S[(size_t)q * NCH * gb1];
    unsigned int e1 = S[(size_t)(q + 1) * NCH * gb1];
    for (unsigned int e = e0 + tid; e < e1; e += 256) {
        int v = bp[e];
        int f = (v & (BSZ - 1)) * NCH + ((unsigned)v >> (BSHIFT + CSHIFT));
        atomicAdd(&h[f], 1u);
    }
    __syncthreads();
    // scan 2048 bins, 8 per thread (thread t owns nodes 2t, 2t+1)
    unsigned int lv[8]; unsigned int tsum = 0;
#pragma unroll
    for (int k = 0; k < 8; ++k) { lv[k] = tsum; tsum += h[8 * tid + k]; }
    ps[tid] = tsum; __syncthreads();
    for (int off = 1; off < 256; off <<= 1) {
        unsigned int u = (tid >= off) ? ps[tid - off] : 0u;
        __syncthreads();
        ps[tid] += u;
        __syncthreads();
    }
    unsigned int excl = ps[tid] - tsum;
#pragma unroll
    for (int k = 0; k < 8; ++k) cur[8 * tid + k] = e0 + excl + lv[k];
#pragma unroll
    for (int k = 0; k < 8; ++k) {
        int idx = base * NCH + 8 * tid + k;
        if (idx < n * NCH) rowptr2[idx] = e0 + excl + lv[k];
    }
    if (q == nbuck - 1 && tid == 0) rowptr2[n * NCH] = (unsigned int)nE;
    int n0 = base + 2 * tid, n1 = n0 + 1;
    unsigned int d0 = h[8 * tid + 0] + h[8 * tid + 1] + h[8 * tid + 2] + h[8 * tid + 3];
    unsigned int d1 = h[8 * tid + 4] + h[8 * tid + 5] + h[8 * tid + 6] + h[8 * tid + 7];
    if (n0 < n) {
        float d = (float)(d0 + 1u); float r = rsqrtf(d);
        r = r * (1.5f - 0.5f * d * r * r); dinv[n0] = r;
    }
    if (n1 < n) {
        float d = (float)(d1 + 1u); float r = rsqrtf(d);
        r = r * (1.5f - 0.5f * d * r * r); dinv[n1] = r;
    }
    __syncthreads();
    for (unsigned int e = e0 + tid; e < e1; e += 256) {
        int v = bp[e];
        int f = (v & (BSZ - 1)) * NCH + ((unsigned)v >> (BSHIFT + CSHIFT));
        unsigned int slot = atomicAdd(&cur[f], 1u);
        col[slot] = (unsigned)v >> BSHIFT;
    }
}

// ---- embeddings + h@W1, pre-scaled by dinv ----
__global__ __launch_bounds__(256) void k_embed(const int* __restrict__ x,
                                               const float* __restrict__ birth_t,
                                               const float* __restrict__ gender_t,
                                               const float* __restrict__ symp_t,
                                               const float* __restrict__ W1,
                                               const float* __restrict__ dinv,
                                               float* __restrict__ hs1, int n) {
    __shared__ float sB[BY * EMB];
    __shared__ float sG[2 * EMB];
    __shared__ float sS[NSYMP * NOPT * EMB];
    __shared__ float sW[EMB * HID];
    for (int k = threadIdx.x; k < BY * EMB; k += blockDim.x) sB[k] = birth_t[k];
    for (int k = threadIdx.x; k < 2 * EMB; k += blockDim.x) sG[k] = gender_t[k];
    for (int k = threadIdx.x; k < NSYMP * NOPT * EMB; k += blockDim.x) sS[k] = symp_t[k];
    for (int k = threadIdx.x; k < EMB * HID; k += blockDim.x) sW[k] = W1[k];
    __syncthreads();

    int i = blockIdx.x * blockDim.x + threadIdx.x;
    if (i >= n) return;

    const int* xr = x + (size_t)i * XCOLS;
    int xv[XCOLS];
#pragma unroll
    for (int k = 0; k < XCOLS; ++k) xv[k] = xr[k];

    int bi = 0;
#pragma unroll
    for (int k = 1; k < BY; ++k) if (xv[k] > xv[bi]) bi = k;
    int gi = xv[BY];

    float ssum[EMB];
#pragma unroll
    for (int k = 0; k < EMB; ++k) ssum[k] = 0.f;
#pragma unroll
    for (int j = 0; j < NSYMP; ++j) {
        const float* row = &sS[(j * NOPT + xv[BY + 1 + j]) * EMB];
#pragma unroll
        for (int k = 0; k < EMB; ++k) ssum[k] += row[k];
    }

    float h[EMB];
#pragma unroll
    for (int k = 0; k < EMB; ++k)
        h[k] = (sB[bi * EMB + k] + sG[gi * EMB + k] + ssum[k] * (1.f / 15.f)) * (1.f / 3.f);

    float hp[HID];
#pragma unroll
    for (int j = 0; j < HID; ++j) hp[j] = 0.f;
#pragma unroll
    for (int k = 0; k < EMB; ++k) {
        float hv = h[k];
#pragma unroll
        for (int j = 0; j < HID; ++j) hp[j] += hv * sW[k * HID + j];
    }

    float dv = dinv[i];
    float4* o = (float4*)(hs1 + (size_t)i * HID);
#pragma unroll
    for (int q = 0; q < 4; ++q) {
        float4 v;
        v.x = dv * hp[q * 4 + 0];
        v.y = dv * hp[q * 4 + 1];
        v.z = dv * hp[q * 4 + 2];
        v.w = dv * hp[q * 4 + 3];
        o[q] = v;
    }
}

// ---- layer 1: quartet-float4 CSR gather + ELU + W2 + z = hs2 . Wl ----
// 16 lanes per node; 4 quartets x float4 -> one dwordx4 instruction moves
// 16 edges' worth of row data per wave. 2 gathers in flight per iteration.
__global__ __launch_bounds__(256) void k_gmid4(const unsigned int* __restrict__ rowptr2,
                                               const int* __restrict__ col,
                                               const float* __restrict__ A,
                                               const float* __restrict__ dinv,
                                               const float* __restrict__ W2,
                                               const float* __restrict__ b1,
                                               const float* __restrict__ Wl,
                                               float* __restrict__ z, int n) {
    __shared__ float sW[HID * HID];
    __shared__ float sb[HID];
    __shared__ float sw[HID];
    __shared__ float sh1[16][HID];           // per-group h1 (transpose buffer)
    if (threadIdx.x < HID * HID) sW[threadIdx.x] = W2[threadIdx.x];
    if (threadIdx.x < HID) { sb[threadIdx.x] = b1[threadIdx.x]; sw[threadIdx.x] = Wl[threadIdx.x]; }
    __syncthreads();

    int gg = threadIdx.x >> 4;               // group (node) within block
    int l  = threadIdx.x & 15;
    int qq = l >> 2, c = l & 3;              // quartet, float4 chunk
    int i = blockIdx.x * 16 + gg;
    bool valid = (i < n);

    unsigned int r0 = 0, r1 = 0;
    if (valid) { r0 = rowptr2[(size_t)i * NCH]; r1 = rowptr2[(size_t)i * NCH + NCH]; }

    float ax = 0.f, ay = 0.f, az = 0.f, aw = 0.f;
    unsigned int e = r0;
    for (; e + 8 <= r1; e += 8) {
        int sA = col[e + qq];
        int sB = col[e + 4 + qq];
        float4 va = *(const float4*)(A + (size_t)sA * HID + c * 4);
        float4 vb = *(const float4*)(A + (size_t)sB * HID + c * 4);
        ax += va.x + vb.x; ay += va.y + vb.y;
        az += va.z + vb.z; aw += va.w + vb.w;
    }
    for (; e + 4 <= r1; e += 4) {
        int sA = col[e + qq];
        float4 va = *(const float4*)(A + (size_t)sA * HID + c * 4);
        ax += va.x; ay += va.y; az += va.z; aw += va.w;
    }
    if (e + qq < r1) {
        int sA = col[e + qq];
        float4 va = *(const float4*)(A + (size_t)sA * HID + c * 4);
        ax += va.x; ay += va.y; az += va.z; aw += va.w;
    }
    // combine across quartets (bits 2,3 of wave lane stay within the group)
    ax += __shfl_xor(ax, 4, 64); ay += __shfl_xor(ay, 4, 64);
    az += __shfl_xor(az, 4, 64); aw += __shfl_xor(aw, 4, 64);
    ax += __shfl_xor(ax, 8, 64); ay += __shfl_xor(ay, 8, 64);
    az += __shfl_xor(az, 8, 64); aw += __shfl_xor(aw, 8, 64);

    float dv = valid ? dinv[i] : 0.f;
    float4 s4 = valid ? *(const float4*)(A + (size_t)i * HID + c * 4)
                      : make_float4(0.f, 0.f, 0.f, 0.f);
    float v0 = dv * (ax + s4.x) + sb[c * 4 + 0];
    float v1 = dv * (ay + s4.y) + sb[c * 4 + 1];
    float v2 = dv * (az + s4.z) + sb[c * 4 + 2];
    float v3 = dv * (aw + s4.w) + sb[c * 4 + 3];
    float h0 = (v0 > 0.f) ? v0 : expm1f(v0);
    float h1 = (v1 > 0.f) ? v1 : expm1f(v1);
    float h2 = (v2 > 0.f) ? v2 : expm1f(v2);
    float h3 = (v3 > 0.f) ? v3 : expm1f(v3);
    if (qq == 0) {
        float4 hv = make_float4(h0, h1, h2, h3);
        *(float4*)&sh1[gg][c * 4] = hv;
    }
    __syncthreads();

    // epilogue: lane l owns component l of node gg
    float hp = 0.f;
#pragma unroll
    for (int k = 0; k < HID; ++k) hp += sh1[gg][k] * sW[k * HID + l];
    float p = dv * hp * sw[l];
#pragma unroll
    for (int off = 8; off > 0; off >>= 1) p += __shfl_xor(p, off, 64);
    if (l == 0 && valid) z[i] = p;
}

// ---- layer 2: scalar z gather, 8 partials in flight + final affine ----
__global__ __launch_bounds__(256) void k_gfin4(const unsigned int* __restrict__ rowptr2,
                                               const int* __restrict__ col,
                                               const float* __restrict__ z,
                                               const float* __restrict__ dinv,
                                               const float* __restrict__ b2,
                                               const float* __restrict__ Wl,
                                               const float* __restrict__ bl,
                                               float* __restrict__ out, int n) {
    __shared__ float sc0;
    if (threadIdx.x == 0) {
        float c = 0.f;
#pragma unroll
        for (int k = 0; k < HID; ++k) c += b2[k] * Wl[k];
        sc0 = c + bl[0];
    }
    __syncthreads();

    int i = blockIdx.x * blockDim.x + threadIdx.x;
    if (i >= n) return;

    unsigned int r0 = rowptr2[(size_t)i * NCH];
    unsigned int r1 = rowptr2[(size_t)i * NCH + NCH];
    float s0 = 0.f, s1 = 0.f, s2 = 0.f, s3 = 0.f;
    float s4 = 0.f, s5 = 0.f, s6 = 0.f, s7 = 0.f;
    unsigned int e = r0;
    for (; e + 8 <= r1; e += 8) {
        s0 += z[col[e + 0]]; s1 += z[col[e + 1]];
        s2 += z[col[e + 2]]; s3 += z[col[e + 3]];
        s4 += z[col[e + 4]]; s5 += z[col[e + 5]];
        s6 += z[col[e + 6]]; s7 += z[col[e + 7]];
    }
    for (; e < r1; ++e) s0 += z[col[e]];
    float s = ((s0 + s1) + (s2 + s3)) + ((s4 + s5) + (s6 + s7));
    out[i] = dinv[i] * (s + z[i]) + sc0;
}

extern "C" void kernel_launch(void* const* d_in, const int* in_sizes, int n_in,
                              void* d_out, int out_size, void* d_ws, size_t ws_size,
                              hipStream_t stream) {
    const int*   x        = (const int*)d_in[0];
    const int*   ei       = (const int*)d_in[1];   // int32 per harness conversion
    const float* birth_t  = (const float*)d_in[2];
    const float* gender_t = (const float*)d_in[3];
    const float* symp_t   = (const float*)d_in[4];
    const float* W1       = (const float*)d_in[5];
    const float* b1       = (const float*)d_in[6];
    const float* W2       = (const float*)d_in[7];
    const float* b2       = (const float*)d_in[8];
    const float* Wl       = (const float*)d_in[9];
    const float* bl       = (const float*)d_in[10];
    float*       out      = (float*)d_out;

    const int n  = in_sizes[0] / XCOLS;
    const int nE = in_sizes[1] / 2;
    const int* src = ei;
    const int* tgt = ei + nE;

    const int nbuck = (n + BSZ - 1) >> BSHIFT;            // 391
    const int nbins = nbuck * NCH;                        // 1564 (<= NBINS_CAP)
    const int gb1   = (nE + EPB - 1) / EPB;               // 782
    const int M     = nbins * gb1;                        // ~1.22M
    const int nb    = (M + SCAN_B - 1) / SCAN_B;          // ~150 (<=512)

    // workspace layout (256B aligned slices)
    char* ws = (char*)d_ws;
    size_t off = 0;
    auto alloc = [&](size_t bytes) { char* p = ws + off; off = (off + bytes + 255) & ~(size_t)255; return p; };
    unsigned int* H       = (unsigned int*)alloc((size_t)M * 4);
    unsigned int* S       = (unsigned int*)alloc(((size_t)M + 1) * 4);
    unsigned int* bsum    = (unsigned int*)alloc(512 * 4);
    unsigned int* boff    = (unsigned int*)alloc(512 * 4);
    int*          bp      = (int*)alloc((size_t)nE * 4);
    int*          col     = (int*)alloc((size_t)nE * 4);
    unsigned int* rowptr2 = (unsigned int*)alloc(((size_t)n * NCH + 1) * 4);
    float*        dinv    = (float*)alloc((size_t)n * 4);
    float*        A       = (float*)alloc((size_t)n * HID * 4);
    float*        z       = (float*)alloc((size_t)n * 4);

    const int BLK = 256;
    const int gN    = (n + BLK - 1) / BLK;
    const int gNode = (n + 15) / 16;

    k_hist <<<gb1, BLK, 0, stream>>>(tgt, src, H, nE, gb1, nbins);
    k_bsum <<<nb, SCAN_T, 0, stream>>>(H, bsum, M);
    k_bscan<<<1, 512, 0, stream>>>(bsum, boff, nb);
    k_scan2<<<nb, SCAN_T, 0, stream>>>(H, boff, S, M, nE);
    k_scat <<<gb1, BLK, 0, stream>>>(tgt, src, S, bp, nE, gb1, nbins);
    k_bcsr <<<nbuck, BLK, 0, stream>>>(S, bp, rowptr2, col, dinv, n, nE, gb1, nbuck);
    k_embed<<<gN, BLK, 0, stream>>>(x, birth_t, gender_t, symp_t, W1, dinv, A, n);
    k_gmid4<<<gNode, BLK, 0, stream>>>(rowptr2, col, A, dinv, W2, b1, Wl, z, n);
    k_gfin4<<<gN, BLK, 0, stream>>>(rowptr2, col, z, dinv, b2, Wl, bl, out, n);
}